// Round 1
// baseline (723.369 us; speedup 1.0000x reference)
//
#include <hip/hip_runtime.h>

#define NN 20000
#define NE 640000
#define DIM 128
#define ND (NN * DIM)

typedef float f32x4 __attribute__((ext_vector_type(4)));
typedef __bf16 bf16x4 __attribute__((ext_vector_type(4)));
typedef __bf16 bf16x8 __attribute__((ext_vector_type(8)));

// XOR-swizzle for [rows][128] bf16 LDS tiles: spreads the 16B frag slots of
// 8 consecutive rows across 8 distinct bank groups (G4 fix; else 16-way
// conflict on ds_read_b128 at 256B row stride).
__device__ __forceinline__ int swz(int r, int c) {
  return r * DIM + (c ^ ((r & 7) << 3));
}

// ---------------------------------------------------------------------------
// prep: convert 5 weight matrices f32->bf16 into ws; fold BN into scale/shift
// wbf layout: [Wa, Wb, Wd, We, Wc], each DIM*DIM
// bn layout:  [scale_h, shift_h, scale_e, shift_e], each DIM floats
// ---------------------------------------------------------------------------
__global__ void prep(const float* __restrict__ Wa, const float* __restrict__ Wb,
                     const float* __restrict__ Wd, const float* __restrict__ We,
                     const float* __restrict__ Wc, __bf16* __restrict__ wbf,
                     const float* __restrict__ gh, const float* __restrict__ bh,
                     const float* __restrict__ mh, const float* __restrict__ vh,
                     const float* __restrict__ ge, const float* __restrict__ be_,
                     const float* __restrict__ me, const float* __restrict__ ve,
                     float* __restrict__ bn) {
  int g = blockIdx.x * 256 + threadIdx.x;   // grid = 320 blocks -> g < 81920
  int m = g >> 14;
  int off = g & 16383;
  const float* s = (m == 0) ? Wa : (m == 1) ? Wb : (m == 2) ? Wd : (m == 3) ? We : Wc;
  wbf[g] = (__bf16)s[off];
  if (g < DIM) {
    float sc = gh[g] * rsqrtf(vh[g] + 1e-5f);
    bn[g] = sc;
    bn[DIM + g] = bh[g] - mh[g] * sc;
  } else if (g < 2 * DIM) {
    int c = g - DIM;
    float sc = ge[c] * rsqrtf(ve[c] + 1e-5f);
    bn[2 * DIM + c] = sc;
    bn[3 * DIM + c] = be_[c] - me[c] * sc;
  }
}

// ---------------------------------------------------------------------------
// node_gemm: Ah/Bh/Dh/Eh = h @ {Wa,Wb,Wd,We}.T + bias    (64-row tiles)
// ---------------------------------------------------------------------------
__global__ __launch_bounds__(256) void node_gemm(
    const float* __restrict__ h, const __bf16* __restrict__ wbf,
    const float* __restrict__ ba, const float* __restrict__ bb,
    const float* __restrict__ bd, const float* __restrict__ be,
    float* __restrict__ Ah, float* __restrict__ Bh,
    float* __restrict__ Dh, float* __restrict__ Eh) {
  __shared__ __bf16 As[64 * DIM];
  __shared__ __bf16 Ws[DIM * DIM];
  const int tid = threadIdx.x;
  const int row0 = blockIdx.x * 64;

  // stage A tile (64 x 128 f32 -> bf16, swizzled)
#pragma unroll
  for (int it = 0; it < 8; ++it) {
    int flat = it * 1024 + tid * 4;
    int r = flat >> 7, c = flat & 127;
    int grow = row0 + r;
    f32x4 v;
    if (grow < NN) v = *(const f32x4*)(h + grow * DIM + c);
    else v = (f32x4){0.f, 0.f, 0.f, 0.f};
    bf16x4 b;
    b[0] = (__bf16)v[0]; b[1] = (__bf16)v[1];
    b[2] = (__bf16)v[2]; b[3] = (__bf16)v[3];
    *(bf16x4*)(As + swz(r, c)) = b;
  }

  const int wv = tid >> 6, lane = tid & 63;
  const int lq = lane >> 4, lm = lane & 15;

#pragma unroll 1
  for (int m = 0; m < 4; ++m) {
    __syncthreads();   // A staged (m=0) / previous Ws reads done (m>0)
#pragma unroll
    for (int it = 0; it < 8; ++it) {
      int chunk = it * 256 + tid;              // 8-elem chunks
      int r = chunk >> 4, c0 = (chunk & 15) << 3;
      bf16x8 v = *(const bf16x8*)(wbf + m * DIM * DIM + (chunk << 3));
      *(bf16x8*)(Ws + swz(r, c0)) = v;
    }
    __syncthreads();

    f32x4 acc[8];
#pragma unroll
    for (int i = 0; i < 8; ++i) acc[i] = (f32x4){0.f, 0.f, 0.f, 0.f};
#pragma unroll
    for (int ks = 0; ks < 4; ++ks) {
      int k0 = ks * 32 + lq * 8;
      int ar = wv * 16 + lm;
      bf16x8 a = *(const bf16x8*)(As + swz(ar, k0));
#pragma unroll
      for (int nt = 0; nt < 8; ++nt) {
        int bcol = nt * 16 + lm;
        bf16x8 b = *(const bf16x8*)(Ws + swz(bcol, k0));
        acc[nt] = __builtin_amdgcn_mfma_f32_16x16x32_bf16(a, b, acc[nt], 0, 0, 0);
      }
    }
    const float* bias = (m == 0) ? ba : (m == 1) ? bb : (m == 2) ? bd : be;
    float* out = (m == 0) ? Ah : (m == 1) ? Bh : (m == 2) ? Dh : Eh;
#pragma unroll
    for (int nt = 0; nt < 8; ++nt) {
      int col = nt * 16 + lm;
      float bv = bias[col];
#pragma unroll
      for (int r = 0; r < 4; ++r) {
        int grow = row0 + wv * 16 + lq * 4 + r;
        if (grow < NN) out[grow * DIM + col] = acc[nt][r] + bv;
      }
    }
  }
}

// ---------------------------------------------------------------------------
// edge_gemm: Ce = e @ Wc.T + bc; e_new = Ce + Dh[src] + Eh[dst];
//            sigma = sigmoid(e_new); atomic num/den; e_out = relu(BN(e_new))
// ---------------------------------------------------------------------------
__global__ __launch_bounds__(256) void edge_gemm(
    const float* __restrict__ e, const __bf16* __restrict__ wc,
    const int* __restrict__ src, const int* __restrict__ dst,
    const float* __restrict__ bc,
    const float* __restrict__ Bh, const float* __restrict__ Dh,
    const float* __restrict__ Eh,
    float* __restrict__ num, float* __restrict__ den,
    float* __restrict__ e_out, const float* __restrict__ bn) {
  __shared__ __bf16 As[64 * DIM];
  __shared__ __bf16 Ws[DIM * DIM];
  __shared__ int s_src[64];
  __shared__ int s_dst[64];
  const int tid = threadIdx.x;
  const int e0 = blockIdx.x * 64;

#pragma unroll
  for (int it = 0; it < 8; ++it) {
    int flat = it * 1024 + tid * 4;
    int r = flat >> 7, c = flat & 127;
    f32x4 v = *(const f32x4*)(e + (size_t)(e0 + r) * DIM + c);
    bf16x4 b;
    b[0] = (__bf16)v[0]; b[1] = (__bf16)v[1];
    b[2] = (__bf16)v[2]; b[3] = (__bf16)v[3];
    *(bf16x4*)(As + swz(r, c)) = b;
  }
#pragma unroll
  for (int it = 0; it < 8; ++it) {
    int chunk = it * 256 + tid;
    int r = chunk >> 4, c0 = (chunk & 15) << 3;
    bf16x8 v = *(const bf16x8*)(wc + (chunk << 3));
    *(bf16x8*)(Ws + swz(r, c0)) = v;
  }
  if (tid < 64) s_src[tid] = src[e0 + tid];
  else if (tid < 128) s_dst[tid - 64] = dst[e0 + tid - 64];
  __syncthreads();

  const int wv = tid >> 6, lane = tid & 63;
  const int lq = lane >> 4, lm = lane & 15;

  f32x4 acc[8];
#pragma unroll
  for (int i = 0; i < 8; ++i) acc[i] = (f32x4){0.f, 0.f, 0.f, 0.f};
#pragma unroll
  for (int ks = 0; ks < 4; ++ks) {
    int k0 = ks * 32 + lq * 8;
    int ar = wv * 16 + lm;
    bf16x8 a = *(const bf16x8*)(As + swz(ar, k0));
#pragma unroll
    for (int nt = 0; nt < 8; ++nt) {
      int bcol = nt * 16 + lm;
      bf16x8 b = *(const bf16x8*)(Ws + swz(bcol, k0));
      acc[nt] = __builtin_amdgcn_mfma_f32_16x16x32_bf16(a, b, acc[nt], 0, 0, 0);
    }
  }

  const float* scale_e = bn + 2 * DIM;
  const float* shift_e = bn + 3 * DIM;
#pragma unroll
  for (int nt = 0; nt < 8; ++nt) {
    int col = nt * 16 + lm;
    float bcv = bc[col];
    float sc = scale_e[col], sh = shift_e[col];
#pragma unroll
    for (int r = 0; r < 4; ++r) {
      int lrow = wv * 16 + lq * 4 + r;
      int edge = e0 + lrow;
      int s = s_src[lrow], dn = s_dst[lrow];
      float x = acc[nt][r] + bcv + Dh[s * DIM + col] + Eh[dn * DIM + col];
      float sig = 1.0f / (1.0f + __expf(-x));
      e_out[(size_t)edge * DIM + col] = fmaxf(sc * x + sh, 0.0f);
      atomicAdd(num + dn * DIM + col, sig * Bh[s * DIM + col]);
      atomicAdd(den + dn * DIM + col, sig);
    }
  }
}

// ---------------------------------------------------------------------------
// final_h: h_out = relu(BN_h(Ah + num/(den+1e-6)))
// ---------------------------------------------------------------------------
__global__ void final_h(const float* __restrict__ Ah, const float* __restrict__ num,
                        const float* __restrict__ den, const float* __restrict__ bn,
                        float* __restrict__ h_out) {
  int g = blockIdx.x * blockDim.x + threadIdx.x;   // 0 .. ND/4
  int idx = g * 4;
  int col = idx & (DIM - 1);
  f32x4 a = *(const f32x4*)(Ah + idx);
  f32x4 n = *(const f32x4*)(num + idx);
  f32x4 d = *(const f32x4*)(den + idx);
  f32x4 o;
#pragma unroll
  for (int j = 0; j < 4; ++j) {
    float hn = a[j] + n[j] / (d[j] + 1e-6f);
    o[j] = fmaxf(bn[col + j] * hn + bn[DIM + col + j], 0.0f);
  }
  *(f32x4*)(h_out + idx) = o;
}

// ---------------------------------------------------------------------------
extern "C" void kernel_launch(void* const* d_in, const int* in_sizes, int n_in,
                              void* d_out, int out_size, void* d_ws, size_t ws_size,
                              hipStream_t stream) {
  (void)in_sizes; (void)n_in; (void)out_size; (void)ws_size;
  const float* h   = (const float*)d_in[0];
  const float* e   = (const float*)d_in[1];
  const int*   src = (const int*)d_in[2];
  const int*   dst = (const int*)d_in[3];
  const float* Wa  = (const float*)d_in[4];
  const float* ba  = (const float*)d_in[5];
  const float* Wb  = (const float*)d_in[6];
  const float* bb  = (const float*)d_in[7];
  const float* Wc  = (const float*)d_in[8];
  const float* bc  = (const float*)d_in[9];
  const float* Wd  = (const float*)d_in[10];
  const float* bd  = (const float*)d_in[11];
  const float* We  = (const float*)d_in[12];
  const float* be  = (const float*)d_in[13];
  const float* gamma_h = (const float*)d_in[14];
  const float* beta_h  = (const float*)d_in[15];
  const float* mean_h  = (const float*)d_in[16];
  const float* var_h   = (const float*)d_in[17];
  const float* gamma_e = (const float*)d_in[18];
  const float* beta_e  = (const float*)d_in[19];
  const float* mean_e  = (const float*)d_in[20];
  const float* var_e   = (const float*)d_in[21];

  float* ws  = (float*)d_ws;
  float* Ah  = ws;
  float* Bh  = Ah + ND;
  float* Dh  = Bh + ND;
  float* Eh  = Dh + ND;
  float* num = Eh + ND;
  float* den = num + ND;
  __bf16* wbf = (__bf16*)(den + ND);          // 5 * DIM*DIM bf16
  float* bn  = (float*)(wbf + 5 * DIM * DIM); // 4 * DIM f32

  float* h_out = (float*)d_out;
  float* e_out = h_out + ND;

  hipMemsetAsync(num, 0, (size_t)2 * ND * sizeof(float), stream);
  prep<<<320, 256, 0, stream>>>(Wa, Wb, Wd, We, Wc, wbf,
                                gamma_h, beta_h, mean_h, var_h,
                                gamma_e, beta_e, mean_e, var_e, bn);
  node_gemm<<<(NN + 63) / 64, 256, 0, stream>>>(h, wbf, ba, bb, bd, be,
                                                Ah, Bh, Dh, Eh);
  edge_gemm<<<NE / 64, 256, 0, stream>>>(e, wbf + 4 * DIM * DIM, src, dst, bc,
                                         Bh, Dh, Eh, num, den, e_out, bn);
  final_h<<<ND / 4 / 256, 256, 0, stream>>>(Ah, num, den, bn, h_out);
}

// Round 2
// 409.838 us; speedup vs baseline: 1.7650x; 1.7650x over previous
//
#include <hip/hip_runtime.h>

#define NN 20000
#define NE 640000
#define DIM 128
#define ND (NN * DIM)

typedef float f32x4 __attribute__((ext_vector_type(4)));
typedef __bf16 bf16x4 __attribute__((ext_vector_type(4)));
typedef __bf16 bf16x8 __attribute__((ext_vector_type(8)));

// XOR-swizzle for [rows][128] bf16 LDS tiles read as ds_read_b128 (G4 fix).
__device__ __forceinline__ int swz(int r, int c) {
  return r * DIM + (c ^ ((r & 7) << 3));
}
// Swizzle for the reduction stash: makes the epilogue's per-fragment b16
// stores land 2-way (free) instead of 8-way. XOR constant per row -> bijective.
__device__ __forceinline__ int swzr(int r, int c) {
  return r * DIM + (c ^ ((r & 3) << 3) ^ (((r >> 2) & 3) << 4));
}

// ---------------------------------------------------------------------------
// prep: weights f32->bf16; fold BN into scale/shift
// ---------------------------------------------------------------------------
__global__ void prep(const float* __restrict__ Wa, const float* __restrict__ Wb,
                     const float* __restrict__ Wd, const float* __restrict__ We,
                     const float* __restrict__ Wc, __bf16* __restrict__ wbf,
                     const float* __restrict__ gh, const float* __restrict__ bh,
                     const float* __restrict__ mh, const float* __restrict__ vh,
                     const float* __restrict__ ge, const float* __restrict__ be_,
                     const float* __restrict__ me, const float* __restrict__ ve,
                     float* __restrict__ bn) {
  int g = blockIdx.x * 256 + threadIdx.x;   // 320 blocks -> g < 81920
  int m = g >> 14;
  int off = g & 16383;
  const float* s = (m == 0) ? Wa : (m == 1) ? Wb : (m == 2) ? Wd : (m == 3) ? We : Wc;
  wbf[g] = (__bf16)s[off];
  if (g < DIM) {
    float sc = gh[g] * rsqrtf(vh[g] + 1e-5f);
    bn[g] = sc;
    bn[DIM + g] = bh[g] - mh[g] * sc;
  } else if (g < 2 * DIM) {
    int c = g - DIM;
    float sc = ge[c] * rsqrtf(ve[c] + 1e-5f);
    bn[2 * DIM + c] = sc;
    bn[3 * DIM + c] = be_[c] - me[c] * sc;
  }
}

// ---------------------------------------------------------------------------
// counting sort of edges by dst:  hist -> scan (1 block) -> scatter
// ---------------------------------------------------------------------------
__global__ void hist(const int* __restrict__ dst, int* __restrict__ cur) {
  int e = blockIdx.x * 256 + threadIdx.x;
  if (e < NE) atomicAdd(cur + dst[e], 1);
}

__global__ __launch_bounds__(1024) void scan20k(int* __restrict__ cur) {
  __shared__ int wsum[16];
  int tid = threadIdx.x;
  int wid = tid >> 6, lane = tid & 63;
  int carry = 0;
  for (int base = 0; base < NN; base += 1024) {
    int i = base + tid;
    int v = (i < NN) ? cur[i] : 0;
    int x = v;
#pragma unroll
    for (int d = 1; d < 64; d <<= 1) {
      int y = __shfl_up(x, d, 64);
      if (lane >= d) x += y;
    }
    if (lane == 63) wsum[wid] = x;
    __syncthreads();
    if (wid == 0 && lane < 16) {
      int s = wsum[lane];
#pragma unroll
      for (int d = 1; d < 16; d <<= 1) {
        int y = __shfl_up(s, d, 64);
        if (lane >= d) s += y;
      }
      wsum[lane] = s;
    }
    __syncthreads();
    int woff = (wid > 0) ? wsum[wid - 1] : 0;
    if (i < NN) cur[i] = carry + woff + x - v;   // exclusive prefix
    carry += wsum[15];
    __syncthreads();
  }
}

__global__ void scatter(const int* __restrict__ dst, int* __restrict__ cur,
                        int* __restrict__ perm) {
  int e = blockIdx.x * 256 + threadIdx.x;
  if (e < NE) {
    int p = atomicAdd(cur + dst[e], 1);
    perm[p] = e;
  }
}

// ---------------------------------------------------------------------------
// node_gemm: Ah/Bh/Dh/Eh = h @ {Wa,Wb,Wd,We}.T + bias    (64-row tiles)
// ---------------------------------------------------------------------------
__global__ __launch_bounds__(256) void node_gemm(
    const float* __restrict__ h, const __bf16* __restrict__ wbf,
    const float* __restrict__ ba, const float* __restrict__ bb,
    const float* __restrict__ bd, const float* __restrict__ be,
    float* __restrict__ Ah, float* __restrict__ Bh,
    float* __restrict__ Dh, float* __restrict__ Eh) {
  __shared__ __bf16 As[64 * DIM];
  __shared__ __bf16 Ws[DIM * DIM];
  const int tid = threadIdx.x;
  const int row0 = blockIdx.x * 64;

#pragma unroll
  for (int it = 0; it < 8; ++it) {
    int flat = it * 1024 + tid * 4;
    int r = flat >> 7, c = flat & 127;
    int grow = row0 + r;
    f32x4 v;
    if (grow < NN) v = *(const f32x4*)(h + grow * DIM + c);
    else v = (f32x4){0.f, 0.f, 0.f, 0.f};
    bf16x4 b;
    b[0] = (__bf16)v[0]; b[1] = (__bf16)v[1];
    b[2] = (__bf16)v[2]; b[3] = (__bf16)v[3];
    *(bf16x4*)(As + swz(r, c)) = b;
  }

  const int wv = tid >> 6, lane = tid & 63;
  const int lq = lane >> 4, lm = lane & 15;

#pragma unroll 1
  for (int m = 0; m < 4; ++m) {
    __syncthreads();
#pragma unroll
    for (int it = 0; it < 8; ++it) {
      int chunk = it * 256 + tid;
      int r = chunk >> 4, c0 = (chunk & 15) << 3;
      bf16x8 v = *(const bf16x8*)(wbf + m * DIM * DIM + (chunk << 3));
      *(bf16x8*)(Ws + swz(r, c0)) = v;
    }
    __syncthreads();

    f32x4 acc[8];
#pragma unroll
    for (int i = 0; i < 8; ++i) acc[i] = (f32x4){0.f, 0.f, 0.f, 0.f};
#pragma unroll
    for (int ks = 0; ks < 4; ++ks) {
      int k0 = ks * 32 + lq * 8;
      int ar = wv * 16 + lm;
      bf16x8 a = *(const bf16x8*)(As + swz(ar, k0));
#pragma unroll
      for (int nt = 0; nt < 8; ++nt) {
        int bcol = nt * 16 + lm;
        bf16x8 b = *(const bf16x8*)(Ws + swz(bcol, k0));
        acc[nt] = __builtin_amdgcn_mfma_f32_16x16x32_bf16(a, b, acc[nt], 0, 0, 0);
      }
    }
    const float* bias = (m == 0) ? ba : (m == 1) ? bb : (m == 2) ? bd : be;
    float* out = (m == 0) ? Ah : (m == 1) ? Bh : (m == 2) ? Dh : Eh;
#pragma unroll
    for (int nt = 0; nt < 8; ++nt) {
      int col = nt * 16 + lm;
      float bv = bias[col];
#pragma unroll
      for (int r = 0; r < 4; ++r) {
        int grow = row0 + wv * 16 + lq * 4 + r;
        if (grow < NN) out[grow * DIM + col] = acc[nt][r] + bv;
      }
    }
  }
}

// ---------------------------------------------------------------------------
// edge_gemm (dst-sorted): Ce = e[perm] @ Wc.T; e_new = Ce + Dh[src] + Eh[dst];
// e_out[perm] = relu(BN(e_new)); block-local segmented reduce of
// (sigma, sigma*Bh[src]) by dst -> few atomics per segment boundary.
// ---------------------------------------------------------------------------
union SmemU {
  struct { __bf16 As[64 * DIM]; __bf16 Ws[DIM * DIM]; } g;
  struct { __bf16 sg[64 * DIM]; __bf16 sb[64 * DIM]; } r;
};

__global__ __launch_bounds__(256) void edge_gemm(
    const float* __restrict__ e, const __bf16* __restrict__ wc,
    const int* __restrict__ src, const int* __restrict__ dst,
    const int* __restrict__ perm, const float* __restrict__ bc,
    const float* __restrict__ Bh, const float* __restrict__ Dh,
    const float* __restrict__ Eh,
    float* __restrict__ num, float* __restrict__ den,
    float* __restrict__ e_out, const float* __restrict__ bn) {
  __shared__ SmemU u;
  __shared__ int s_perm[64], s_src[64], s_dst[64];
  const int tid = threadIdx.x;
  const int e0 = blockIdx.x * 64;

  if (tid < 64) {
    int p = perm[e0 + tid];
    s_perm[tid] = p;
    s_src[tid] = src[p];
    s_dst[tid] = dst[p];
  }
  // stage Wc (doesn't need perm)
#pragma unroll
  for (int it = 0; it < 8; ++it) {
    int chunk = it * 256 + tid;
    int r = chunk >> 4, c0 = (chunk & 15) << 3;
    bf16x8 v = *(const bf16x8*)(wc + (chunk << 3));
    *(bf16x8*)(u.g.Ws + swz(r, c0)) = v;
  }
  __syncthreads();

  // stage A tile: gathered rows e[perm]
#pragma unroll
  for (int it = 0; it < 8; ++it) {
    int flat = it * 1024 + tid * 4;
    int r = flat >> 7, c = flat & 127;
    f32x4 v = *(const f32x4*)(e + (size_t)s_perm[r] * DIM + c);
    bf16x4 b;
    b[0] = (__bf16)v[0]; b[1] = (__bf16)v[1];
    b[2] = (__bf16)v[2]; b[3] = (__bf16)v[3];
    *(bf16x4*)(u.g.As + swz(r, c)) = b;
  }
  __syncthreads();

  const int wv = tid >> 6, lane = tid & 63;
  const int lq = lane >> 4, lm = lane & 15;

  f32x4 acc[8];
#pragma unroll
  for (int i = 0; i < 8; ++i) acc[i] = (f32x4){0.f, 0.f, 0.f, 0.f};
#pragma unroll
  for (int ks = 0; ks < 4; ++ks) {
    int k0 = ks * 32 + lq * 8;
    int ar = wv * 16 + lm;
    bf16x8 a = *(const bf16x8*)(u.g.As + swz(ar, k0));
#pragma unroll
    for (int nt = 0; nt < 8; ++nt) {
      int bcol = nt * 16 + lm;
      bf16x8 b = *(const bf16x8*)(u.g.Ws + swz(bcol, k0));
      acc[nt] = __builtin_amdgcn_mfma_f32_16x16x32_bf16(a, b, acc[nt], 0, 0, 0);
    }
  }
  __syncthreads();   // all waves done reading As/Ws before union reuse

  const float* scale_e = bn + 2 * DIM;
  const float* shift_e = bn + 3 * DIM;
#pragma unroll
  for (int nt = 0; nt < 8; ++nt) {
    int col = nt * 16 + lm;
    float bcv = bc[col];
    float sc = scale_e[col], sh = shift_e[col];
#pragma unroll
    for (int r = 0; r < 4; ++r) {
      int lrow = wv * 16 + lq * 4 + r;
      int s = s_src[lrow];
      float x = acc[nt][r] + bcv + Dh[s * DIM + col] + Eh[s_dst[lrow] * DIM + col];
      float sig = 1.0f / (1.0f + __expf(-x));
      e_out[(size_t)s_perm[lrow] * DIM + col] = fmaxf(sc * x + sh, 0.0f);
      int a = swzr(lrow, col);
      u.r.sg[a] = (__bf16)sig;
      u.r.sb[a] = (__bf16)(sig * Bh[s * DIM + col]);
    }
  }
  __syncthreads();

  // segmented reduction: 2 threads per column, 32 sorted rows each
  {
    int col = tid >> 1;
    int r0 = (tid & 1) << 5;
    float an = 0.f, ad = 0.f;
    int prev = s_dst[r0];
#pragma unroll 4
    for (int k = 0; k < 32; ++k) {
      int row = r0 + k;
      int d = s_dst[row];
      if (d != prev) {
        atomicAdd(num + (size_t)prev * DIM + col, an);
        atomicAdd(den + (size_t)prev * DIM + col, ad);
        an = 0.f; ad = 0.f; prev = d;
      }
      int a = swzr(row, col);
      an += (float)u.r.sb[a];
      ad += (float)u.r.sg[a];
    }
    atomicAdd(num + (size_t)prev * DIM + col, an);
    atomicAdd(den + (size_t)prev * DIM + col, ad);
  }
}

// ---------------------------------------------------------------------------
// final_h: h_out = relu(BN_h(Ah + num/(den+1e-6)))
// ---------------------------------------------------------------------------
__global__ void final_h(const float* __restrict__ Ah, const float* __restrict__ num,
                        const float* __restrict__ den, const float* __restrict__ bn,
                        float* __restrict__ h_out) {
  int g = blockIdx.x * blockDim.x + threadIdx.x;
  int idx = g * 4;
  int col = idx & (DIM - 1);
  f32x4 a = *(const f32x4*)(Ah + idx);
  f32x4 n = *(const f32x4*)(num + idx);
  f32x4 d = *(const f32x4*)(den + idx);
  f32x4 o;
#pragma unroll
  for (int j = 0; j < 4; ++j) {
    float hn = a[j] + n[j] / (d[j] + 1e-6f);
    o[j] = fmaxf(bn[col + j] * hn + bn[DIM + col + j], 0.0f);
  }
  *(f32x4*)(h_out + idx) = o;
}

// ---------------------------------------------------------------------------
extern "C" void kernel_launch(void* const* d_in, const int* in_sizes, int n_in,
                              void* d_out, int out_size, void* d_ws, size_t ws_size,
                              hipStream_t stream) {
  (void)in_sizes; (void)n_in; (void)out_size; (void)ws_size;
  const float* h   = (const float*)d_in[0];
  const float* e   = (const float*)d_in[1];
  const int*   src = (const int*)d_in[2];
  const int*   dst = (const int*)d_in[3];
  const float* Wa  = (const float*)d_in[4];
  const float* ba  = (const float*)d_in[5];
  const float* Wb  = (const float*)d_in[6];
  const float* bb  = (const float*)d_in[7];
  const float* Wc  = (const float*)d_in[8];
  const float* bc  = (const float*)d_in[9];
  const float* Wd  = (const float*)d_in[10];
  const float* bd  = (const float*)d_in[11];
  const float* We  = (const float*)d_in[12];
  const float* be  = (const float*)d_in[13];
  const float* gamma_h = (const float*)d_in[14];
  const float* beta_h  = (const float*)d_in[15];
  const float* mean_h  = (const float*)d_in[16];
  const float* var_h   = (const float*)d_in[17];
  const float* gamma_e = (const float*)d_in[18];
  const float* beta_e  = (const float*)d_in[19];
  const float* mean_e  = (const float*)d_in[20];
  const float* var_e   = (const float*)d_in[21];

  float* ws  = (float*)d_ws;
  float* Ah  = ws;
  float* Bh  = Ah + ND;
  float* Dh  = Bh + ND;
  float* Eh  = Dh + ND;
  float* num = Eh + ND;
  float* den = num + ND;
  __bf16* wbf = (__bf16*)(den + ND);             // 5 * DIM*DIM bf16
  float* bn  = (float*)(wbf + 5 * DIM * DIM);    // 4 * DIM f32
  int*   cur = (int*)(bn + 4 * DIM);             // NN ints (hist -> prefix -> cursor)
  int*   perm = cur + NN;                        // NE ints

  float* h_out = (float*)d_out;
  float* e_out = h_out + ND;

  hipMemsetAsync(num, 0, (size_t)2 * ND * sizeof(float), stream);
  hipMemsetAsync(cur, 0, (size_t)NN * sizeof(int), stream);
  prep<<<320, 256, 0, stream>>>(Wa, Wb, Wd, We, Wc, wbf,
                                gamma_h, beta_h, mean_h, var_h,
                                gamma_e, beta_e, mean_e, var_e, bn);
  hist<<<NE / 256, 256, 0, stream>>>(dst, cur);
  scan20k<<<1, 1024, 0, stream>>>(cur);
  scatter<<<NE / 256, 256, 0, stream>>>(dst, cur, perm);
  node_gemm<<<(NN + 63) / 64, 256, 0, stream>>>(h, wbf, ba, bb, bd, be,
                                                Ah, Bh, Dh, Eh);
  edge_gemm<<<NE / 64, 256, 0, stream>>>(e, wbf + 4 * DIM * DIM, src, dst, perm,
                                         bc, Bh, Dh, Eh, num, den, e_out, bn);
  final_h<<<ND / 4 / 256, 256, 0, stream>>>(Ah, num, den, bn, h_out);
}

// Round 3
// 375.997 us; speedup vs baseline: 1.9239x; 1.0900x over previous
//
#include <hip/hip_runtime.h>

#define NN 20000
#define NE 640000
#define DIM 128
#define ND (NN * DIM)

typedef float f32x4 __attribute__((ext_vector_type(4)));
typedef __bf16 bf16x4 __attribute__((ext_vector_type(4)));
typedef __bf16 bf16x8 __attribute__((ext_vector_type(8)));

// XOR-swizzle for [rows][128] bf16 LDS tiles read as ds_read_b128 (G4 fix).
__device__ __forceinline__ int swz(int r, int c) {
  return r * DIM + (c ^ ((r & 7) << 3));
}
// Swizzle for the reduction stash (2B elements, col-walk read).
__device__ __forceinline__ int swzr(int r, int c) {
  return r * DIM + (c ^ ((r & 3) << 3) ^ (((r >> 2) & 3) << 4));
}

// ---------------------------------------------------------------------------
// prep: node weights f32->bf16 (wbf = [Wa,Wb,Wd,We]); Wc packed into MFMA
// fragment order (wcp); BN folded into scale/shift.
// wcp chunk index (ks*8+nt)*64+lane holds Wc[nt*16+(lane&15)][ks*32+(lane>>4)*8 .. +8]
// ---------------------------------------------------------------------------
__global__ void prep(const float* __restrict__ Wa, const float* __restrict__ Wb,
                     const float* __restrict__ Wd, const float* __restrict__ We,
                     const float* __restrict__ Wc, __bf16* __restrict__ wbf,
                     __bf16* __restrict__ wcp,
                     const float* __restrict__ gh, const float* __restrict__ bh,
                     const float* __restrict__ mh, const float* __restrict__ vh,
                     const float* __restrict__ ge, const float* __restrict__ be_,
                     const float* __restrict__ me, const float* __restrict__ ve,
                     float* __restrict__ bn) {
  int b = blockIdx.x;
  int tid = threadIdx.x;
  if (b < 256) {
    int g = b * 256 + tid;                  // < 65536
    int m = g >> 14;
    int off = g & 16383;
    const float* s = (m == 0) ? Wa : (m == 1) ? Wb : (m == 2) ? Wd : We;
    wbf[g] = (__bf16)s[off];
    if (g < DIM) {
      float sc = gh[g] * rsqrtf(vh[g] + 1e-5f);
      bn[g] = sc;
      bn[DIM + g] = bh[g] - mh[g] * sc;
    } else if (g < 2 * DIM) {
      int c = g - DIM;
      float sc = ge[c] * rsqrtf(ve[c] + 1e-5f);
      bn[2 * DIM + c] = sc;
      bn[3 * DIM + c] = be_[c] - me[c] * sc;
    }
  } else {
    int t2 = (b - 256) * 256 + tid;         // < 2048 chunks
    int lane = t2 & 63, nt = (t2 >> 6) & 7, ks = t2 >> 9;
    int lq = lane >> 4, lm = lane & 15;
    const float* srcp = Wc + (nt * 16 + lm) * DIM + ks * 32 + lq * 8;
    bf16x8 v;
#pragma unroll
    for (int j = 0; j < 8; ++j) v[j] = (__bf16)srcp[j];
    *(bf16x8*)(wcp + t2 * 8) = v;
  }
}

// ---------------------------------------------------------------------------
// counting sort of edges by dst: hist -> scan (1 block) -> scatter
// ---------------------------------------------------------------------------
__global__ void hist(const int* __restrict__ dst, int* __restrict__ cur) {
  int e = blockIdx.x * 256 + threadIdx.x;
  if (e < NE) atomicAdd(cur + dst[e], 1);
}

__global__ __launch_bounds__(1024) void scan20k(int* __restrict__ cur) {
  __shared__ int wsum[16];
  int tid = threadIdx.x;
  int wid = tid >> 6, lane = tid & 63;
  int carry = 0;
  for (int base = 0; base < NN; base += 1024) {
    int i = base + tid;
    int v = (i < NN) ? cur[i] : 0;
    int x = v;
#pragma unroll
    for (int d = 1; d < 64; d <<= 1) {
      int y = __shfl_up(x, d, 64);
      if (lane >= d) x += y;
    }
    if (lane == 63) wsum[wid] = x;
    __syncthreads();
    if (wid == 0 && lane < 16) {
      int s = wsum[lane];
#pragma unroll
      for (int d = 1; d < 16; d <<= 1) {
        int y = __shfl_up(s, d, 64);
        if (lane >= d) s += y;
      }
      wsum[lane] = s;
    }
    __syncthreads();
    int woff = (wid > 0) ? wsum[wid - 1] : 0;
    if (i < NN) cur[i] = carry + woff + x - v;   // exclusive prefix
    carry += wsum[15];
    __syncthreads();
  }
}

__global__ void scatter(const int* __restrict__ dst, int* __restrict__ cur,
                        int* __restrict__ perm) {
  int e = blockIdx.x * 256 + threadIdx.x;
  if (e < NE) {
    int p = atomicAdd(cur + dst[e], 1);
    perm[p] = e;
  }
}

// ---------------------------------------------------------------------------
// node_gemm: Ah(f32) = h@Wa.T+ba ; Bhb/Dhb/Ehb (bf16) = h@{Wb,Wd,We}.T+bias
// ---------------------------------------------------------------------------
__global__ __launch_bounds__(256) void node_gemm(
    const float* __restrict__ h, const __bf16* __restrict__ wbf,
    const float* __restrict__ ba, const float* __restrict__ bb,
    const float* __restrict__ bd, const float* __restrict__ be,
    float* __restrict__ Ah, __bf16* __restrict__ Bhb,
    __bf16* __restrict__ Dhb, __bf16* __restrict__ Ehb) {
  __shared__ __bf16 As[64 * DIM];
  __shared__ __bf16 Ws[DIM * DIM];
  const int tid = threadIdx.x;
  const int row0 = blockIdx.x * 64;

#pragma unroll
  for (int it = 0; it < 8; ++it) {
    int flat = it * 1024 + tid * 4;
    int r = flat >> 7, c = flat & 127;
    int grow = row0 + r;
    f32x4 v;
    if (grow < NN) v = *(const f32x4*)(h + grow * DIM + c);
    else v = (f32x4){0.f, 0.f, 0.f, 0.f};
    bf16x4 b;
    b[0] = (__bf16)v[0]; b[1] = (__bf16)v[1];
    b[2] = (__bf16)v[2]; b[3] = (__bf16)v[3];
    *(bf16x4*)(As + swz(r, c)) = b;
  }

  const int wv = tid >> 6, lane = tid & 63;
  const int lq = lane >> 4, lm = lane & 15;

#pragma unroll 1
  for (int m = 0; m < 4; ++m) {
    __syncthreads();
#pragma unroll
    for (int it = 0; it < 8; ++it) {
      int chunk = it * 256 + tid;
      int r = chunk >> 4, c0 = (chunk & 15) << 3;
      bf16x8 v = *(const bf16x8*)(wbf + m * DIM * DIM + (chunk << 3));
      *(bf16x8*)(Ws + swz(r, c0)) = v;
    }
    __syncthreads();

    f32x4 acc[8];
#pragma unroll
    for (int i = 0; i < 8; ++i) acc[i] = (f32x4){0.f, 0.f, 0.f, 0.f};
#pragma unroll
    for (int ks = 0; ks < 4; ++ks) {
      int k0 = ks * 32 + lq * 8;
      int ar = wv * 16 + lm;
      bf16x8 a = *(const bf16x8*)(As + swz(ar, k0));
#pragma unroll
      for (int nt = 0; nt < 8; ++nt) {
        int bcol = nt * 16 + lm;
        bf16x8 b = *(const bf16x8*)(Ws + swz(bcol, k0));
        acc[nt] = __builtin_amdgcn_mfma_f32_16x16x32_bf16(a, b, acc[nt], 0, 0, 0);
      }
    }
    const float* bias = (m == 0) ? ba : (m == 1) ? bb : (m == 2) ? bd : be;
#pragma unroll
    for (int nt = 0; nt < 8; ++nt) {
      int col = nt * 16 + lm;
      float bv = bias[col];
#pragma unroll
      for (int r = 0; r < 4; ++r) {
        int grow = row0 + wv * 16 + lq * 4 + r;
        if (grow < NN) {
          float val = acc[nt][r] + bv;
          if (m == 0) Ah[grow * DIM + col] = val;
          else if (m == 1) Bhb[grow * DIM + col] = (__bf16)val;
          else if (m == 2) Dhb[grow * DIM + col] = (__bf16)val;
          else Ehb[grow * DIM + col] = (__bf16)val;
        }
      }
    }
  }
}

// ---------------------------------------------------------------------------
// edge_gemm (dst-sorted): Ce = e[perm] @ Wc.T (B-frags from global wcp);
// e_new = Ce + Dh[src] + Eh[dst]; e_out[perm] = relu(BN(e_new));
// block-local segmented reduce of (sigma, sigma*Bh[src]) by dst.
// ---------------------------------------------------------------------------
union SmemU {
  __bf16 As[64 * DIM];                                   // 16KB (GEMM phase)
  struct { __bf16 sg[64 * DIM]; __bf16 sb[64 * DIM]; } r; // 32KB (reduce phase)
};

__global__ __launch_bounds__(256, 4) void edge_gemm(
    const float* __restrict__ e, const __bf16* __restrict__ wcp,
    const int* __restrict__ src, const int* __restrict__ dst,
    const int* __restrict__ perm, const float* __restrict__ bc,
    const __bf16* __restrict__ Bhb, const __bf16* __restrict__ Dhb,
    const __bf16* __restrict__ Ehb,
    float* __restrict__ num, float* __restrict__ den,
    float* __restrict__ e_out, const float* __restrict__ bn) {
  __shared__ SmemU u;
  __shared__ int s_perm[64], s_src[64], s_dst[64];
  const int tid = threadIdx.x;
  const int e0 = blockIdx.x * 64;

  if (tid < 64) {
    int p = perm[e0 + tid];
    s_perm[tid] = p;
    s_src[tid] = src[p];
    s_dst[tid] = dst[p];
  }
  __syncthreads();

  // stage A tile: gathered rows e[perm] (non-temporal: streaming, read-once)
#pragma unroll
  for (int it = 0; it < 8; ++it) {
    int flat = it * 1024 + tid * 4;
    int r = flat >> 7, c = flat & 127;
    f32x4 v = __builtin_nontemporal_load(
        (const f32x4*)(e + (size_t)s_perm[r] * DIM + c));
    bf16x4 b;
    b[0] = (__bf16)v[0]; b[1] = (__bf16)v[1];
    b[2] = (__bf16)v[2]; b[3] = (__bf16)v[3];
    *(bf16x4*)(u.As + swz(r, c)) = b;
  }
  __syncthreads();

  const int wv = tid >> 6, lane = tid & 63;
  const int lq = lane >> 4, lm = lane & 15;

  f32x4 acc[8];
#pragma unroll
  for (int i = 0; i < 8; ++i) acc[i] = (f32x4){0.f, 0.f, 0.f, 0.f};
  const bf16x8* wp = (const bf16x8*)wcp;
#pragma unroll
  for (int ks = 0; ks < 4; ++ks) {
    int k0 = ks * 32 + lq * 8;
    int ar = wv * 16 + lm;
    bf16x8 a = *(const bf16x8*)(u.As + swz(ar, k0));
#pragma unroll
    for (int nt = 0; nt < 8; ++nt) {
      bf16x8 b = wp[(ks * 8 + nt) * 64 + lane];   // L1-resident packed Wc
      acc[nt] = __builtin_amdgcn_mfma_f32_16x16x32_bf16(a, b, acc[nt], 0, 0, 0);
    }
  }
  __syncthreads();   // all waves done reading As before union reuse

  const float* scale_e = bn + 2 * DIM;
  const float* shift_e = bn + 3 * DIM;
#pragma unroll
  for (int nt = 0; nt < 8; ++nt) {
    int col = nt * 16 + lm;
    float bcv = bc[col];
    float sc = scale_e[col], sh = shift_e[col];
#pragma unroll
    for (int r = 0; r < 4; ++r) {
      int lrow = wv * 16 + lq * 4 + r;
      int s = s_src[lrow];
      float x = acc[nt][r] + bcv + (float)Dhb[s * DIM + col]
              + (float)Ehb[s_dst[lrow] * DIM + col];
      float sig = 1.0f / (1.0f + __expf(-x));
      __builtin_nontemporal_store(fmaxf(sc * x + sh, 0.0f),
                                  e_out + (size_t)s_perm[lrow] * DIM + col);
      int a = swzr(lrow, col);
      u.r.sg[a] = (__bf16)sig;
      u.r.sb[a] = (__bf16)(sig * (float)Bhb[s * DIM + col]);
    }
  }
  __syncthreads();

  // segmented reduction: 2 threads per column, 32 sorted rows each
  {
    int col = tid >> 1;
    int r0 = (tid & 1) << 5;
    float an = 0.f, ad = 0.f;
    int prev = s_dst[r0];
#pragma unroll 4
    for (int k = 0; k < 32; ++k) {
      int row = r0 + k;
      int d = s_dst[row];
      if (d != prev) {
        atomicAdd(num + (size_t)prev * DIM + col, an);
        atomicAdd(den + (size_t)prev * DIM + col, ad);
        an = 0.f; ad = 0.f; prev = d;
      }
      int a = swzr(row, col);
      an += (float)u.r.sb[a];
      ad += (float)u.r.sg[a];
    }
    atomicAdd(num + (size_t)prev * DIM + col, an);
    atomicAdd(den + (size_t)prev * DIM + col, ad);
  }
}

// ---------------------------------------------------------------------------
// final_h: h_out = relu(BN_h(Ah + num/(den+1e-6)))
// ---------------------------------------------------------------------------
__global__ void final_h(const float* __restrict__ Ah, const float* __restrict__ num,
                        const float* __restrict__ den, const float* __restrict__ bn,
                        float* __restrict__ h_out) {
  int g = blockIdx.x * blockDim.x + threadIdx.x;
  int idx = g * 4;
  int col = idx & (DIM - 1);
  f32x4 a = *(const f32x4*)(Ah + idx);
  f32x4 n = *(const f32x4*)(num + idx);
  f32x4 d = *(const f32x4*)(den + idx);
  f32x4 o;
#pragma unroll
  for (int j = 0; j < 4; ++j) {
    float hn = a[j] + n[j] / (d[j] + 1e-6f);
    o[j] = fmaxf(bn[col + j] * hn + bn[DIM + col + j], 0.0f);
  }
  *(f32x4*)(h_out + idx) = o;
}

// ---------------------------------------------------------------------------
extern "C" void kernel_launch(void* const* d_in, const int* in_sizes, int n_in,
                              void* d_out, int out_size, void* d_ws, size_t ws_size,
                              hipStream_t stream) {
  (void)in_sizes; (void)n_in; (void)out_size; (void)ws_size;
  const float* h   = (const float*)d_in[0];
  const float* e   = (const float*)d_in[1];
  const int*   src = (const int*)d_in[2];
  const int*   dst = (const int*)d_in[3];
  const float* Wa  = (const float*)d_in[4];
  const float* ba  = (const float*)d_in[5];
  const float* Wb  = (const float*)d_in[6];
  const float* bb  = (const float*)d_in[7];
  const float* Wc  = (const float*)d_in[8];
  const float* bc  = (const float*)d_in[9];
  const float* Wd  = (const float*)d_in[10];
  const float* bd  = (const float*)d_in[11];
  const float* We  = (const float*)d_in[12];
  const float* be  = (const float*)d_in[13];
  const float* gamma_h = (const float*)d_in[14];
  const float* beta_h  = (const float*)d_in[15];
  const float* mean_h  = (const float*)d_in[16];
  const float* var_h   = (const float*)d_in[17];
  const float* gamma_e = (const float*)d_in[18];
  const float* beta_e  = (const float*)d_in[19];
  const float* mean_e  = (const float*)d_in[20];
  const float* var_e   = (const float*)d_in[21];

  float* ws  = (float*)d_ws;
  float* Ah  = ws;                                // ND f32
  float* num = Ah + ND;                           // ND f32
  float* den = num + ND;                          // ND f32
  __bf16* Bhb = (__bf16*)(den + ND);              // ND bf16
  __bf16* Dhb = Bhb + ND;                         // ND bf16
  __bf16* Ehb = Dhb + ND;                         // ND bf16
  __bf16* wbf = Ehb + ND;                         // 4*DIM*DIM bf16
  __bf16* wcp = wbf + 4 * DIM * DIM;              // DIM*DIM bf16 (packed)
  float* bn  = (float*)(wcp + DIM * DIM);         // 4*DIM f32
  int*   cur = (int*)(bn + 4 * DIM);              // NN ints
  int*   perm = cur + NN;                         // NE ints

  float* h_out = (float*)d_out;
  float* e_out = h_out + ND;

  hipMemsetAsync(num, 0, (size_t)2 * ND * sizeof(float), stream);
  hipMemsetAsync(cur, 0, (size_t)NN * sizeof(int), stream);
  prep<<<264, 256, 0, stream>>>(Wa, Wb, Wd, We, Wc, wbf, wcp,
                                gamma_h, beta_h, mean_h, var_h,
                                gamma_e, beta_e, mean_e, var_e, bn);
  hist<<<NE / 256, 256, 0, stream>>>(dst, cur);
  scan20k<<<1, 1024, 0, stream>>>(cur);
  scatter<<<NE / 256, 256, 0, stream>>>(dst, cur, perm);
  node_gemm<<<(NN + 63) / 64, 256, 0, stream>>>(h, wbf, ba, bb, bd, be,
                                                Ah, Bhb, Dhb, Ehb);
  edge_gemm<<<NE / 64, 256, 0, stream>>>(e, wcp, src, dst, perm, bc,
                                         Bhb, Dhb, Ehb, num, den, e_out, bn);
  final_h<<<ND / 4 / 256, 256, 0, stream>>>(Ah, num, den, bn, h_out);
}